// Round 9
// baseline (127.881 us; speedup 1.0000x reference)
//
#include <hip/hip_runtime.h>
#include <hip/hip_bf16.h>
#include <stdint.h>

#define SEQ 2048
#define HD  128
#define WIN 512
#define NH  16
#define NKV 4
#define BATCH 2

typedef __attribute__((ext_vector_type(8))) short bf16x8;
typedef __attribute__((ext_vector_type(4))) short bf16x4;
typedef __attribute__((ext_vector_type(4))) float f32x4;
typedef __attribute__((ext_vector_type(4))) uint32_t u32x4;
typedef __attribute__((ext_vector_type(2))) uint32_t u32x2;

// v_exp_f32: D = 2^S0 — avoids the glibc __exp2f macro collision
#define EXP2(x) __builtin_amdgcn_exp2f(x)

#define AS1(p) ((const __attribute__((address_space(1))) uint32_t*)(p))
#define AS3(p) ((__attribute__((address_space(3))) uint32_t*)(p))

__device__ __forceinline__ uint32_t pk2(float a, float b) {
    __hip_bfloat162 h = __float22bfloat162_rn(make_float2(a, b));
    return *reinterpret_cast<uint32_t*>(&h);
}

// ---------------------------------------------------------------------------
// Prep kernel (unchanged from round 8): one block per (kvh, 64-key tile).
//  K -> bf16 rows with 16B-slot XOR swizzle baked in:
//       elem(row,col) = row*128 + ((col>>3) ^ (row&7))*8 + (col&7)
//  V -> bf16 V^T per 64-key tile: [dim][64 keys], key-permutation
//       keypos(key): s=key>>5, h=(key>>4)&1, u=key&15 -> s*32+(u>>2)*8+h*4+(u&3)
//       + same 8-elem XOR swizzle. Two consecutive 64-key tiles compose a
//       128-key stage unit for the main kernel.
// ---------------------------------------------------------------------------
__global__ __launch_bounds__(256) void prep_kv(
    const float* __restrict__ k,
    const float* __restrict__ v,
    uint16_t* __restrict__ kb,   // [8][2048][128]
    uint16_t* __restrict__ vt)   // [8][32][8192]
{
    const int tile = blockIdx.x;        // (kvh*32 + kt64)
    const int kvh  = tile >> 5;
    const int kt   = tile & 31;
    const int t    = threadIdx.x;

    const float* ksrc = k + ((size_t)kvh * SEQ + kt * 64) * HD;
    const float* vsrc = v + ((size_t)kvh * SEQ + kt * 64) * HD;
    uint16_t* kdst = kb + ((size_t)kvh * SEQ + kt * 64) * HD;
    uint16_t* vdst = vt + ((size_t)kvh * 32 + kt) * (size_t)(64 * HD);

    __shared__ uint16_t lv[64][132];   // V tile bf16 (padded rows)

    #pragma unroll
    for (int i = 0; i < 8; ++i) {
        int u = t + i * 256;            // 2048 float4-units
        int row = u >> 5, c4 = u & 31;
        float4 f = *reinterpret_cast<const float4*>(vsrc + row * HD + c4 * 4);
        u32x2 w; w.x = pk2(f.x, f.y); w.y = pk2(f.z, f.w);
        *reinterpret_cast<u32x2*>(&lv[row][c4 * 4]) = w;
    }
    #pragma unroll
    for (int i = 0; i < 8; ++i) {
        int u = t + i * 256;
        int row = u >> 5, c4 = u & 31;
        float4 f = *reinterpret_cast<const float4*>(ksrc + row * HD + c4 * 4);
        u32x2 w; w.x = pk2(f.x, f.y); w.y = pk2(f.z, f.w);
        int col = c4 * 4;
        int e = row * HD + ((((col >> 3) ^ (row & 7)) << 3) | (col & 7));
        *reinterpret_cast<u32x2*>(&kdst[e]) = w;
    }
    __syncthreads();
    #pragma unroll
    for (int i = 0; i < 4; ++i) {
        int g = t + i * 256;            // 1024 granules: dim = g>>3, pg = g&7
        int dim = g >> 3, pg = g & 7;
        uint32_t w[4];
        #pragma unroll
        for (int jj = 0; jj < 4; ++jj) {
            int p0 = pg * 8 + jj * 2;
            int s0 = p0 >> 5, w0 = p0 & 31;
            int key0 = s0 * 32 + ((w0 >> 2) & 1) * 16 + (w0 >> 3) * 4 + (w0 & 3);
            int p1 = p0 + 1;
            int s1 = p1 >> 5, w1 = p1 & 31;
            int key1 = s1 * 32 + ((w1 >> 2) & 1) * 16 + (w1 >> 3) * 4 + (w1 & 3);
            w[jj] = (uint32_t)lv[key0][dim] | ((uint32_t)lv[key1][dim] << 16);
        }
        int e = dim * 64 + ((pg ^ (dim & 7)) << 3);
        u32x4 wv = {w[0], w[1], w[2], w[3]};
        *reinterpret_cast<u32x4*>(&vdst[e]) = wv;
    }
}

// ---------------------------------------------------------------------------
// Main: 8 waves/block, 32 q/wave (2 x 16-row subtiles) -> 256 q/block,
// grid 256 = 1 block/CU. KVBLK=128, K/V double-buffered (128 KB LDS) via
// global_load_lds DMA. K fragments shared across both q-subtiles (32 ds_read
// feed 64 QK MFMAs); V likewise for PV. Softmax per-column (q = lane&15),
// P in registers, PV = 16x16x32 with permuted k-map (B = single b128 read).
// Per-tile fixed costs (barrier, shfl reductions, stage) amortized over
// 2x the rows and 2x the keys of round 8.
// ---------------------------------------------------------------------------
__global__ __launch_bounds__(512) __attribute__((amdgpu_waves_per_eu(2, 2)))
void fa_mfma(
    const float* __restrict__ q,
    const uint16_t* __restrict__ kb,
    const uint16_t* __restrict__ vt,
    float* __restrict__ out)
{
    const int tid  = threadIdx.x;
    const int wave = tid >> 6;             // 0..7
    const int lane = tid & 63;
    const int l4   = lane >> 4;
    const int l15  = lane & 15;

    const int bh   = blockIdx.x >> 3;      // b*NH + h
    const int qblk = blockIdx.x & 7;
    const int q0   = qblk << 8;            // 256 queries per block
    const int hkv  = (bh & (NH - 1)) >> 2; // G = 4
    const int b    = bh >> 4;

    const int i0   = q0 + wave * 32;       // wave's first query row

    __shared__ __align__(16) uint16_t lds_k[2][128 * HD];   // 32 KB each
    __shared__ __align__(16) uint16_t lds_vt[2][128 * HD];  // 32 KB each

    // scale * log2(e): softmax computed in exp2 domain
    const float scale2 = 0.08838834764831845f * 1.4426950408889634f;

    const size_t qbase = (size_t)bh * SEQ * HD;
    const uint16_t* kt_base = kb + (size_t)(b * NKV + hkv) * SEQ * HD;
    const uint16_t* vt_base = vt + (size_t)(b * NKV + hkv) * SEQ * HD;

    // ---- preload Q fragments (B-operand: B[k=dim][n=q], q = l15) ----
    bf16x8 qf[2][4];
    #pragma unroll
    for (int sub = 0; sub < 2; ++sub) {
        const float* qr = q + qbase + (size_t)(i0 + sub * 16 + l15) * HD;
        #pragma unroll
        for (int ks = 0; ks < 4; ++ks) {
            const float4* g = reinterpret_cast<const float4*>(qr + ks * 32 + l4 * 8);
            float4 a = g[0], bq = g[1];
            u32x4 t;
            t.x = pk2(a.x * scale2, a.y * scale2);
            t.y = pk2(a.z * scale2, a.w * scale2);
            t.z = pk2(bq.x * scale2, bq.y * scale2);
            t.w = pk2(bq.z * scale2, bq.w * scale2);
            qf[sub][ks] = __builtin_bit_cast(bf16x8, t);
        }
    }

    f32x4 O[2][8];
    #pragma unroll
    for (int a1 = 0; a1 < 2; ++a1)
        #pragma unroll
        for (int a2 = 0; a2 < 8; ++a2) O[a1][a2] = (f32x4){0.f, 0.f, 0.f, 0.f};
    float mrow[2] = {-1e30f, -1e30f};
    float lrow[2] = {0.f, 0.f};

    // 128-key tile indices
    const int kt_lo_blk = (q0 >= 512) ? ((q0 - 511) >> 7) : 0;
    const int kt_hi_blk = (q0 + 255) >> 7;
    const int lo_w = (i0 >= 512) ? ((i0 - 511) >> 7) : 0;
    const int hi_w = (i0 + 31) >> 7;

    // ---- DMA staging: 4x16B K + 4x16B V per thread per 128-key tile ----
    auto stage = [&](int kt, int pb) {
        const uint16_t* ks = kt_base + (size_t)kt * 128 * HD;
        const uint16_t* vs = vt_base + (size_t)kt * 128 * HD;
        #pragma unroll
        for (int c = 0; c < 4; ++c) {
            const int off = c * 4096 + tid * 8;
            __builtin_amdgcn_global_load_lds(AS1(ks + off), AS3(&lds_k[pb][off]),
                                             16, 0, 0);
            __builtin_amdgcn_global_load_lds(AS1(vs + off), AS3(&lds_vt[pb][off]),
                                             16, 0, 0);
        }
    };

    stage(kt_lo_blk, 0);
    __syncthreads();   // drains vmcnt -> buffer 0 ready

    int par = 0;
    for (int kt = kt_lo_blk; kt <= kt_hi_blk; ++kt) {
        if (kt < kt_hi_blk) stage(kt + 1, par ^ 1);  // fire-and-forget DMA

        if (kt >= lo_w && kt <= hi_w) {
            // ---------- S^T = K · Q^T (64 MFMAs, K reads shared by subs) ----
            f32x4 sf[2][8];
            #pragma unroll
            for (int sub = 0; sub < 2; ++sub)
                #pragma unroll
                for (int mt = 0; mt < 8; ++mt) sf[sub][mt] = (f32x4){0.f, 0.f, 0.f, 0.f};
            __builtin_amdgcn_s_setprio(1);
            #pragma unroll
            for (int mt = 0; mt < 8; ++mt) {
                const int arow = mt * 16 + l15;
                #pragma unroll
                for (int ks = 0; ks < 4; ++ks) {
                    bf16x8 af = *reinterpret_cast<const bf16x8*>(
                        &lds_k[par][arow * HD + ((((ks * 4 + l4) ^ (arow & 7))) << 3)]);
                    sf[0][mt] = __builtin_amdgcn_mfma_f32_16x16x32_bf16(
                        af, qf[0][ks], sf[0][mt], 0, 0, 0);
                    sf[1][mt] = __builtin_amdgcn_mfma_f32_16x16x32_bf16(
                        af, qf[1][ks], sf[1][mt], 0, 0, 0);
                }
            }
            __builtin_amdgcn_s_setprio(0);
            // ---------- mask (window-entry and causal-edge tiles only) ------
            const bool needmask = (kt == hi_w) || (kt == lo_w && i0 >= 512);
            if (needmask) {
                #pragma unroll
                for (int sub = 0; sub < 2; ++sub) {
                    const int iq = i0 + sub * 16 + l15;
                    #pragma unroll
                    for (int mt = 0; mt < 8; ++mt) {
                        int jb = kt * 128 + mt * 16 + l4 * 4;
                        #pragma unroll
                        for (int r = 0; r < 4; ++r) {
                            int j = jb + r;
                            if (!((j <= iq) && (iq - j < WIN))) sf[sub][mt][r] = -1e30f;
                        }
                    }
                }
            }
            // ---------- online softmax per subtile, defer-max (THR=8) -------
            bf16x4 pfrag[2][8];
            #pragma unroll
            for (int sub = 0; sub < 2; ++sub) {
                float tmx = -1e30f;
                #pragma unroll
                for (int mt = 0; mt < 8; ++mt) {
                    float a = fmaxf(fmaxf(sf[sub][mt][0], sf[sub][mt][1]),
                                    fmaxf(sf[sub][mt][2], sf[sub][mt][3]));
                    tmx = fmaxf(tmx, a);
                }
                tmx = fmaxf(tmx, __shfl_xor(tmx, 16, 64));
                tmx = fmaxf(tmx, __shfl_xor(tmx, 32, 64));
                const bool defer = __all(tmx <= mrow[sub] + 8.0f);
                if (!defer) {
                    float mn = fmaxf(mrow[sub], tmx);
                    float alpha = EXP2(mrow[sub] - mn);
                    mrow[sub] = mn;
                    lrow[sub] *= alpha;
                    #pragma unroll
                    for (int r = 0; r < 4; ++r) {
                        float ar = __shfl(alpha, l4 * 4 + r, 64);
                        #pragma unroll
                        for (int nt = 0; nt < 8; ++nt) O[sub][nt][r] *= ar;
                    }
                }
                float me = fmaxf(mrow[sub], -1e20f);   // fully-masked rows -> p=0
                float ts = 0.f;
                #pragma unroll
                for (int mt = 0; mt < 8; ++mt) {
                    float p0 = EXP2(sf[sub][mt][0] - me);
                    float p1 = EXP2(sf[sub][mt][1] - me);
                    float p2 = EXP2(sf[sub][mt][2] - me);
                    float p3 = EXP2(sf[sub][mt][3] - me);
                    u32x2 t;
                    t.x = pk2(p0, p1);
                    t.y = pk2(p2, p3);
                    pfrag[sub][mt] = __builtin_bit_cast(bf16x4, t);
                    ts += (p0 + p1) + (p2 + p3);
                }
                ts += __shfl_xor(ts, 16, 64);
                ts += __shfl_xor(ts, 32, 64);
                lrow[sub] += ts;
            }
            // ---------- O += P · V  (64 MFMAs; V reads shared by subs) ------
            // pa = concat(pfrag[2s], pfrag[2s+1]): slot j <-> key
            // s*32 + (j>>2)*16 + l4*4 + (j&3); V^T key-perm (per 64-key half
            // st = s>>1, s2 = s&1) makes B one contiguous swizzled b128.
            __builtin_amdgcn_s_setprio(1);
            #pragma unroll
            for (int s = 0; s < 4; ++s) {
                const int st = s >> 1, s2 = s & 1;
                bf16x8 pa0 = __builtin_shufflevector(pfrag[0][2 * s], pfrag[0][2 * s + 1],
                                                     0, 1, 2, 3, 4, 5, 6, 7);
                bf16x8 pa1 = __builtin_shufflevector(pfrag[1][2 * s], pfrag[1][2 * s + 1],
                                                     0, 1, 2, 3, 4, 5, 6, 7);
                #pragma unroll
                for (int nt = 0; nt < 8; ++nt) {
                    const int vr = nt * 16 + l15;
                    bf16x8 vf = *reinterpret_cast<const bf16x8*>(
                        &lds_vt[par][st * 8192 + vr * 64 +
                                     ((((s2 * 4 + l4) ^ (vr & 7))) << 3)]);
                    O[0][nt] = __builtin_amdgcn_mfma_f32_16x16x32_bf16(
                        pa0, vf, O[0][nt], 0, 0, 0);
                    O[1][nt] = __builtin_amdgcn_mfma_f32_16x16x32_bf16(
                        pa1, vf, O[1][nt], 0, 0, 0);
                }
            }
            __builtin_amdgcn_s_setprio(0);
        }
        __syncthreads();   // all reads of par done + next-tile DMA drained
        par ^= 1;
    }

    // ---------- epilogue: O / l, f32 out ----------
    #pragma unroll
    for (int sub = 0; sub < 2; ++sub) {
        float inv = 1.0f / lrow[sub];
        #pragma unroll
        for (int r = 0; r < 4; ++r) {
            float li = __shfl(inv, l4 * 4 + r, 64);
            int row = i0 + sub * 16 + l4 * 4 + r;
            float* orow = out + qbase + (size_t)row * HD;
            #pragma unroll
            for (int nt = 0; nt < 8; ++nt)
                orow[nt * 16 + l15] = O[sub][nt][r] * li;
        }
    }
}

// ---------------------------------------------------------------------------
// Fallback (round-6 fused kernel, verbatim): used only if d_ws is too small
// for the 8 MB prep workspace, so the submission never writes out-of-bounds.
// ---------------------------------------------------------------------------
#define KSTR 136
#define VSTR 72
#define VT_ROWS (HD * VSTR + (HD / 4) * 4)
__device__ __forceinline__ int vt_off(int row, int col) {
    return row * VSTR + (row >> 2) * 4 + col;
}

__global__ __launch_bounds__(512, 2)
void fa_mfma_fused(
    const float* __restrict__ q,
    const float* __restrict__ k,
    const float* __restrict__ v,
    float* __restrict__ out)
{
    const int tid  = threadIdx.x;
    const int wave = tid >> 6;
    const int lane = tid & 63;
    const int l4   = lane >> 4;
    const int l15  = lane & 15;

    const int bh   = blockIdx.x >> 4;
    const int qblk = blockIdx.x & 15;
    const int q0   = qblk << 7;
    const int hkv  = (bh & (NH - 1)) >> 2;
    const int b    = bh >> 4;

    const int i0   = q0 + wave * 16;

    __shared__ __align__(16) uint16_t lds_k[2][64 * KSTR];
    __shared__ __align__(16) uint16_t lds_vt[2][VT_ROWS];

    const float scale2 = 0.08838834764831845f * 1.4426950408889634f;

    const size_t qbase  = (size_t)bh * SEQ * HD;
    const size_t kvbase = (size_t)(b * NKV + hkv) * SEQ * HD;

    bf16x8 qf[4];
    {
        const float* qr = q + qbase + (size_t)(i0 + l15) * HD;
        #pragma unroll
        for (int ks = 0; ks < 4; ++ks) {
            const float4* g = reinterpret_cast<const float4*>(qr + ks * 32 + l4 * 8);
            float4 a = g[0], bq = g[1];
            u32x4 t;
            t.x = pk2(a.x * scale2, a.y * scale2);
            t.y = pk2(a.z * scale2, a.w * scale2);
            t.z = pk2(bq.x * scale2, bq.y * scale2);
            t.w = pk2(bq.z * scale2, bq.w * scale2);
            qf[ks] = __builtin_bit_cast(bf16x8, t);
        }
    }

    f32x4 O[8];
    #pragma unroll
    for (int a2 = 0; a2 < 8; ++a2) O[a2] = (f32x4){0.f, 0.f, 0.f, 0.f};
    float mrow = -1e30f;
    float lrow = 0.f;

    const int kt_lo_blk = (q0 >= 512) ? ((q0 - 511) >> 6) : 0;
    const int kt_hi_blk = (q0 + 127) >> 6;
    const int lo_w = (i0 >= 512) ? ((i0 - 511) >> 6) : 0;
    const int hi_w = (i0 + 15) >> 6;

    const int vdg = tid & 31;
    const int vkg = tid >> 5;
    float4 rKa[2], rKb[2], rV[4];

    auto prefetch_k = [&](int kt) {
        const float* kp = k + kvbase + (size_t)kt * 64 * HD;
        #pragma unroll
        for (int it = 0; it < 2; ++it) {
            int flat8 = tid + it * 512, key = flat8 >> 4, ch = flat8 & 15;
            const float4* g = reinterpret_cast<const float4*>(kp + key * HD + ch * 8);
            rKa[it] = g[0]; rKb[it] = g[1];
        }
    };
    auto prefetch_v = [&](int kt) {
        const float* vp = v + kvbase + (size_t)kt * 64 * HD;
        #pragma unroll
        for (int r = 0; r < 4; ++r)
            rV[r] = *reinterpret_cast<const float4*>(vp + (vkg * 4 + r) * HD + vdg * 4);
    };
    auto pack_k = [&](int pb) {
        #pragma unroll
        for (int it = 0; it < 2; ++it) {
            int flat8 = tid + it * 512, key = flat8 >> 4, ch = flat8 & 15;
            uint4 wv;
            wv.x = pk2(rKa[it].x, rKa[it].y);  wv.y = pk2(rKa[it].z, rKa[it].w);
            wv.z = pk2(rKb[it].x, rKb[it].y);  wv.w = pk2(rKb[it].z, rKb[it].w);
            *reinterpret_cast<uint4*>(&lds_k[pb][key * KSTR + ch * 8]) = wv;
        }
    };
    auto pack_v = [&](int pb) {
        const float* rvf = reinterpret_cast<const float*>(rV);
        #pragma unroll
        for (int i = 0; i < 4; ++i) {
            u32x2 wv;
            wv.x = pk2(rvf[0 * 4 + i], rvf[1 * 4 + i]);
            wv.y = pk2(rvf[2 * 4 + i], rvf[3 * 4 + i]);
            *reinterpret_cast<u32x2*>(&lds_vt[pb][vt_off(vdg * 4 + i, vkg * 4)]) = wv;
        }
    };

    prefetch_k(kt_lo_blk);
    prefetch_v(kt_lo_blk);
    pack_k(0);
    pack_v(0);
    __syncthreads();

    int par = 0;
    for (int kt = kt_lo_blk; kt <= kt_hi_blk; ++kt) {
        const bool more = (kt < kt_hi_blk);
        if (more) prefetch_k(kt + 1);

        if (kt >= lo_w && kt <= hi_w) {
            f32x4 sf[4];
            #pragma unroll
            for (int mt = 0; mt < 4; ++mt) sf[mt] = (f32x4){0.f, 0.f, 0.f, 0.f};
            __builtin_amdgcn_s_setprio(1);
            #pragma unroll
            for (int mt = 0; mt < 4; ++mt) {
                #pragma unroll
                for (int ks = 0; ks < 4; ++ks) {
                    bf16x8 af = *reinterpret_cast<const bf16x8*>(
                        &lds_k[par][(mt * 16 + l15) * KSTR + ks * 32 + l4 * 8]);
                    sf[mt] = __builtin_amdgcn_mfma_f32_16x16x32_bf16(
                        af, qf[ks], sf[mt], 0, 0, 0);
                }
            }
            __builtin_amdgcn_s_setprio(0);
            if (more) { pack_k(par ^ 1); prefetch_v(kt + 1); }
            const bool needmask = (kt == hi_w) || (kt == lo_w && i0 > 511);
            if (needmask) {
                const int iq = i0 + l15;
                #pragma unroll
                for (int mt = 0; mt < 4; ++mt) {
                    int jb = kt * 64 + mt * 16 + l4 * 4;
                    #pragma unroll
                    for (int r = 0; r < 4; ++r) {
                        int j = jb + r;
                        if (!((j <= iq) && (iq - j < WIN))) sf[mt][r] = -1e30f;
                    }
                }
            }
            float a0 = fmaxf(fmaxf(sf[0][0], sf[0][1]), fmaxf(sf[0][2], sf[0][3]));
            float a1 = fmaxf(fmaxf(sf[1][0], sf[1][1]), fmaxf(sf[1][2], sf[1][3]));
            float a2 = fmaxf(fmaxf(sf[2][0], sf[2][1]), fmaxf(sf[2][2], sf[2][3]));
            float a3 = fmaxf(fmaxf(sf[3][0], sf[3][1]), fmaxf(sf[3][2], sf[3][3]));
            float tm = fmaxf(fmaxf(a0, a1), fmaxf(a2, a3));
            tm = fmaxf(tm, __shfl_xor(tm, 16, 64));
            tm = fmaxf(tm, __shfl_xor(tm, 32, 64));
            const bool defer = __all(tm <= mrow + 8.0f);
            if (!defer) {
                float mn = fmaxf(mrow, tm);
                float alpha = EXP2(mrow - mn);
                mrow = mn;
                lrow *= alpha;
                #pragma unroll
                for (int r = 0; r < 4; ++r) {
                    float ar = __shfl(alpha, l4 * 4 + r, 64);
                    #pragma unroll
                    for (int nt = 0; nt < 8; ++nt) O[nt][r] *= ar;
                }
            }
            bf16x4 pfrag[4];
            {
                float me = fmaxf(mrow, -1e20f);
                float s[4];
                #pragma unroll
                for (int mt = 0; mt < 4; ++mt) {
                    float p0 = EXP2(sf[mt][0] - me);
                    float p1 = EXP2(sf[mt][1] - me);
                    float p2 = EXP2(sf[mt][2] - me);
                    float p3 = EXP2(sf[mt][3] - me);
                    u32x2 t;
                    t.x = pk2(p0, p1);
                    t.y = pk2(p2, p3);
                    pfrag[mt] = __builtin_bit_cast(bf16x4, t);
                    s[mt] = (p0 + p1) + (p2 + p3);
                }
                float ts = (s[0] + s[1]) + (s[2] + s[3]);
                ts += __shfl_xor(ts, 16, 64);
                ts += __shfl_xor(ts, 32, 64);
                lrow += ts;
            }
            if (more) pack_v(par ^ 1);
            __builtin_amdgcn_s_setprio(1);
            #pragma unroll
            for (int s = 0; s < 2; ++s) {
                bf16x8 pa = __builtin_shufflevector(pfrag[2 * s], pfrag[2 * s + 1],
                                                    0, 1, 2, 3, 4, 5, 6, 7);
                #pragma unroll
                for (int nt = 0; nt < 8; ++nt) {
                    const int vr = nt * 16 + l15;
                    bf16x4 v0 = *reinterpret_cast<const bf16x4*>(
                        &lds_vt[par][vt_off(vr, s * 32 + l4 * 4)]);
                    bf16x4 v1 = *reinterpret_cast<const bf16x4*>(
                        &lds_vt[par][vt_off(vr, s * 32 + 16 + l4 * 4)]);
                    bf16x8 vf = __builtin_shufflevector(v0, v1, 0, 1, 2, 3, 4, 5, 6, 7);
                    O[nt] = __builtin_amdgcn_mfma_f32_16x16x32_bf16(pa, vf, O[nt], 0, 0, 0);
                }
            }
            __builtin_amdgcn_s_setprio(0);
        } else {
            if (more) { prefetch_v(kt + 1); pack_k(par ^ 1); pack_v(par ^ 1); }
        }
        __syncthreads();
        par ^= 1;
    }

    {
        float inv = 1.0f / lrow;
        #pragma unroll
        for (int r = 0; r < 4; ++r) {
            float li = __shfl(inv, l4 * 4 + r, 64);
            int row = i0 + l4 * 4 + r;
            float* orow = out + qbase + (size_t)row * HD;
            #pragma unroll
            for (int nt = 0; nt < 8; ++nt)
                orow[nt * 16 + l15] = O[nt][r] * li;
        }
    }
}

extern "C" void kernel_launch(void* const* d_in, const int* in_sizes, int n_in,
                              void* d_out, int out_size, void* d_ws, size_t ws_size,
                              hipStream_t stream) {
    const float* q = (const float*)d_in[0];
    const float* k = (const float*)d_in[1];
    const float* v = (const float*)d_in[2];
    float* out     = (float*)d_out;

    const size_t kv_elems = (size_t)BATCH * NKV * SEQ * HD;    // 2,097,152
    const size_t ws_needed = kv_elems * 2u * sizeof(uint16_t); // 8 MB

    if (d_ws != nullptr && ws_size >= ws_needed) {
        uint16_t* kb  = (uint16_t*)d_ws;           // 4 MB
        uint16_t* vtw = kb + kv_elems;             // 4 MB
        hipLaunchKernelGGL(prep_kv, dim3(BATCH * NKV * (SEQ / 64)), dim3(256), 0,
                           stream, k, v, kb, vtw);
        hipLaunchKernelGGL(fa_mfma, dim3(BATCH * NH * (SEQ / 256)), dim3(512), 0,
                           stream, q, kb, vtw, out);
    } else {
        hipLaunchKernelGGL(fa_mfma_fused, dim3(BATCH * NH * (SEQ / 128)), dim3(512),
                           0, stream, q, k, v, out);
    }
}

// Round 10
// 121.031 us; speedup vs baseline: 1.0566x; 1.0566x over previous
//
#include <hip/hip_runtime.h>
#include <hip/hip_bf16.h>
#include <stdint.h>

#define SEQ 2048
#define HD  128
#define WIN 512
#define NH  16
#define NKV 4
#define BATCH 2

typedef __attribute__((ext_vector_type(8))) short bf16x8;
typedef __attribute__((ext_vector_type(4))) short bf16x4;
typedef __attribute__((ext_vector_type(4))) float f32x4;
typedef __attribute__((ext_vector_type(16))) float f32x16;
typedef __attribute__((ext_vector_type(4))) uint32_t u32x4;
typedef __attribute__((ext_vector_type(2))) uint32_t u32x2;

// v_exp_f32: D = 2^S0 — avoids the glibc __exp2f macro collision
#define EXP2(x) __builtin_amdgcn_exp2f(x)

#define AS1(p) ((const __attribute__((address_space(1))) uint32_t*)(p))
#define AS3(p) ((__attribute__((address_space(3))) uint32_t*)(p))

__device__ __forceinline__ uint32_t pk2(float a, float b) {
    __hip_bfloat162 h = __float22bfloat162_rn(make_float2(a, b));
    return *reinterpret_cast<uint32_t*>(&h);
}

// ---------------------------------------------------------------------------
// Prep kernel: one block per (kvh, 64-key tile).
//  K -> bf16 rows [key][128] with 16B-slot XOR swizzle baked in:
//       elem(row,col) = row*128 + ((col>>3) ^ (row&7))*8 + (col&7)
//  V -> bf16 V^T per tile [d][64 keys], arranged for 32x32x16 PV:
//       per d-row, 8 granules of 8 keys; granule g = s*2+h (s = 16-key step,
//       h = lane-half), element j -> key s*16 + 4h + (j&3) + 8*(j>>2)
//       (matches the A-operand keys available per lane from the 32x32 S^T
//        C-layout), stored at granule' = g ^ (d&7) (bank spread).
// Main kernel stages both via linear global_load_lds (rule #21: linear LDS
// dest + pre-swizzled global source + swizzled LDS reads).
// ---------------------------------------------------------------------------
__global__ __launch_bounds__(256) void prep_kv(
    const float* __restrict__ k,
    const float* __restrict__ v,
    uint16_t* __restrict__ kb,   // [8][2048][128]
    uint16_t* __restrict__ vt)   // [8][32][8192]
{
    const int tile = blockIdx.x;        // (kvh*32 + kt64)
    const int kvh  = tile >> 5;
    const int kt   = tile & 31;
    const int t    = threadIdx.x;

    const float* ksrc = k + ((size_t)kvh * SEQ + kt * 64) * HD;
    const float* vsrc = v + ((size_t)kvh * SEQ + kt * 64) * HD;
    uint16_t* kdst = kb + ((size_t)kvh * SEQ + kt * 64) * HD;
    uint16_t* vdst = vt + ((size_t)kvh * 32 + kt) * (size_t)(64 * HD);

    __shared__ uint16_t lv[64][132];   // V tile bf16 (padded rows)

    #pragma unroll
    for (int i = 0; i < 8; ++i) {
        int u = t + i * 256;            // 2048 float4-units
        int row = u >> 5, c4 = u & 31;
        float4 f = *reinterpret_cast<const float4*>(vsrc + row * HD + c4 * 4);
        u32x2 w; w.x = pk2(f.x, f.y); w.y = pk2(f.z, f.w);
        *reinterpret_cast<u32x2*>(&lv[row][c4 * 4]) = w;
    }
    #pragma unroll
    for (int i = 0; i < 8; ++i) {
        int u = t + i * 256;
        int row = u >> 5, c4 = u & 31;
        float4 f = *reinterpret_cast<const float4*>(ksrc + row * HD + c4 * 4);
        u32x2 w; w.x = pk2(f.x, f.y); w.y = pk2(f.z, f.w);
        int col = c4 * 4;
        int e = row * HD + ((((col >> 3) ^ (row & 7)) << 3) | (col & 7));
        *reinterpret_cast<u32x2*>(&kdst[e]) = w;
    }
    __syncthreads();
    // V^T readout: 1024 granules (d 0..127 x g 0..7), 16B each
    #pragma unroll
    for (int i = 0; i < 4; ++i) {
        int gid = t + i * 256;
        int d = gid >> 3, g = gid & 7;
        int s = g >> 1, h = g & 1;
        uint32_t w[4];
        #pragma unroll
        for (int jj = 0; jj < 4; ++jj) {
            int j0 = 2 * jj;
            int key0 = s * 16 + h * 4 + (j0 & 3) + ((j0 >> 2) << 3);
            w[jj] = (uint32_t)lv[key0][d] | ((uint32_t)lv[key0 + 1][d] << 16);
        }
        int e = d * 64 + ((g ^ (d & 7)) << 3);
        u32x4 wv = {w[0], w[1], w[2], w[3]};
        *reinterpret_cast<u32x4*>(&vdst[e]) = wv;
    }
}

// ---------------------------------------------------------------------------
// Main: 4 waves/block (256 thr), 32 q/wave via 32x32x16 MFMAs -> 128 q/block,
// grid 512 = 2 blocks/CU (two barrier domains — the R8 property that won the
// R8/R9 A/B). KVBLK=64 double-buffered (64 KB LDS) via global_load_lds DMA.
// 32x32 halves LDS bytes per FLOP on both K(A) and V(B) reads, and each wave
// covers 2x the q-rows -> LDS-port pressure (the R8 dominant term, ~63%)
// drops ~2.4x. S^T = K·Q^T: per lane q = lane&31, keys in 16 regs
// (row=(reg&3)+8*(reg>>2)+4h); softmax reduce = 1 shfl_xor(32).
// P stays in registers and feeds PV's A-operand directly (key<->slot
// bijection baked into V^T by prep).
// ---------------------------------------------------------------------------
__global__ __launch_bounds__(256) __attribute__((amdgpu_waves_per_eu(2, 2)))
void fa_mfma(
    const float* __restrict__ q,
    const uint16_t* __restrict__ kb,
    const uint16_t* __restrict__ vt,
    float* __restrict__ out)
{
    const int tid  = threadIdx.x;
    const int wave = tid >> 6;             // 0..3
    const int lane = tid & 63;
    const int l31  = lane & 31;
    const int h    = lane >> 5;            // lane half
    const int hs   = h << 2;               // +4 row offset for upper half

    const int bh   = blockIdx.x >> 4;      // b*NH + h
    const int qblk = blockIdx.x & 15;
    const int q0   = qblk << 7;            // 128 queries per block
    const int hkv  = (bh & (NH - 1)) >> 2; // G = 4
    const int b    = bh >> 4;

    const int i0   = q0 + wave * 32;       // wave's first query row

    __shared__ __align__(16) uint16_t lds_k[2][64 * HD];   // 16 KB each
    __shared__ __align__(16) uint16_t lds_vt[2][64 * HD];  // 16 KB each

    // scale * log2(e): softmax computed in exp2 domain
    const float scale2 = 0.08838834764831845f * 1.4426950408889634f;

    const size_t qbase = (size_t)bh * SEQ * HD;
    const uint16_t* kt_base = kb + (size_t)(b * NKV + hkv) * SEQ * HD;
    const uint16_t* vt_base = vt + (size_t)(b * NKV + hkv) * SEQ * HD;

    // ---- preload Q fragments (B-operand: col=q=lane&31, k=h*8+j) ----
    bf16x8 qf[8];
    {
        const float* qr = q + qbase + (size_t)(i0 + l31) * HD;
        #pragma unroll
        for (int dk = 0; dk < 8; ++dk) {
            const float4* g = reinterpret_cast<const float4*>(qr + dk * 16 + h * 8);
            float4 a = g[0], bq = g[1];
            u32x4 t;
            t.x = pk2(a.x * scale2, a.y * scale2);
            t.y = pk2(a.z * scale2, a.w * scale2);
            t.z = pk2(bq.x * scale2, bq.y * scale2);
            t.w = pk2(bq.z * scale2, bq.w * scale2);
            qf[dk] = __builtin_bit_cast(bf16x8, t);
        }
    }

    f32x16 O[4];
    #pragma unroll
    for (int nt = 0; nt < 4; ++nt)
        #pragma unroll
        for (int r = 0; r < 16; ++r) O[nt][r] = 0.f;
    float mrow = -1e30f;
    float lrow = 0.f;

    const int kt_lo_blk = (q0 >= 512) ? ((q0 - 511) >> 6) : 0;
    const int kt_hi_blk = (q0 + 127) >> 6;
    const int lo_w = (i0 >= 512) ? ((i0 - 511) >> 6) : 0;
    const int hi_w = (i0 + 31) >> 6;

    // ---- DMA staging: 4x16B K + 4x16B V per thread per 64-key tile ----
    auto stage = [&](int kt, int pb) {
        const uint16_t* ks = kt_base + (size_t)kt * 64 * HD;
        const uint16_t* vs = vt_base + (size_t)kt * 64 * HD;
        #pragma unroll
        for (int c = 0; c < 4; ++c) {
            const int off = c * 2048 + tid * 8;
            __builtin_amdgcn_global_load_lds(AS1(ks + off), AS3(&lds_k[pb][off]),
                                             16, 0, 0);
            __builtin_amdgcn_global_load_lds(AS1(vs + off), AS3(&lds_vt[pb][off]),
                                             16, 0, 0);
        }
    };

    stage(kt_lo_blk, 0);
    __syncthreads();   // drains vmcnt -> buffer 0 ready

    int par = 0;
    for (int kt = kt_lo_blk; kt <= kt_hi_blk; ++kt) {
        if (kt < kt_hi_blk) stage(kt + 1, par ^ 1);  // fire-and-forget DMA

        if (kt >= lo_w && kt <= hi_w) {
            // ---------- S^T = K · Q^T (16 MFMAs, 32x32x16) ----------
            f32x16 sf[2];
            #pragma unroll
            for (int mt = 0; mt < 2; ++mt)
                #pragma unroll
                for (int r = 0; r < 16; ++r) sf[mt][r] = 0.f;
            __builtin_amdgcn_s_setprio(1);
            #pragma unroll
            for (int dk = 0; dk < 8; ++dk) {
                #pragma unroll
                for (int mt = 0; mt < 2; ++mt) {
                    const int krow = mt * 32 + l31;
                    bf16x8 af = *reinterpret_cast<const bf16x8*>(
                        &lds_k[par][krow * HD + (((dk * 2 + h) ^ (krow & 7)) << 3)]);
                    sf[mt] = __builtin_amdgcn_mfma_f32_32x32x16_bf16(
                        af, qf[dk], sf[mt], 0, 0, 0);
                }
            }
            __builtin_amdgcn_s_setprio(0);
            // ---------- mask (window-entry and causal-edge tiles only) ------
            const bool needmask = (kt == hi_w) || (kt == lo_w && i0 > 511);
            if (needmask) {
                const int iq = i0 + l31;
                #pragma unroll
                for (int mt = 0; mt < 2; ++mt) {
                    #pragma unroll
                    for (int r = 0; r < 16; ++r) {
                        int j = kt * 64 + mt * 32 + (r & 3) + ((r >> 2) << 3) + hs;
                        if (!((j <= iq) && (iq - j < WIN))) sf[mt][r] = -1e30f;
                    }
                }
            }
            // ---------- online softmax, exp2 domain, defer-max (THR=8) ------
            float tmx = sf[0][0];
            #pragma unroll
            for (int r = 1; r < 16; ++r) tmx = fmaxf(tmx, sf[0][r]);
            #pragma unroll
            for (int r = 0; r < 16; ++r) tmx = fmaxf(tmx, sf[1][r]);
            tmx = fmaxf(tmx, __shfl_xor(tmx, 32, 64));
            const bool defer = __all(tmx <= mrow + 8.0f);
            if (!defer) {
                float mn = fmaxf(mrow, tmx);
                float alpha = EXP2(mrow - mn);
                mrow = mn;
                lrow *= alpha;
                #pragma unroll
                for (int r = 0; r < 16; ++r) {
                    float ar = __shfl(alpha, (r & 3) + ((r >> 2) << 3) + hs, 64);
                    #pragma unroll
                    for (int nt = 0; nt < 4; ++nt) O[nt][r] *= ar;
                }
            }
            // ---------- P in registers (bf16 pairs), per-q sums -------------
            uint32_t pf[2][8];
            {
                float me = fmaxf(mrow, -1e20f);   // fully-masked rows -> p = 0
                float ts = 0.f;
                #pragma unroll
                for (int mt = 0; mt < 2; ++mt) {
                    #pragma unroll
                    for (int rr = 0; rr < 8; ++rr) {
                        float p0 = EXP2(sf[mt][2 * rr] - me);
                        float p1 = EXP2(sf[mt][2 * rr + 1] - me);
                        pf[mt][rr] = pk2(p0, p1);
                        ts += p0 + p1;
                    }
                }
                ts += __shfl_xor(ts, 32, 64);
                lrow += ts;
            }
            // ---------- O += P · V  (16 MFMAs, 32x32x16) --------------------
            // A slot j (half h) <-> key s*16 + 4h + (j&3) + 8*(j>>2) — the
            // same map prep baked into V^T, so B = one contiguous b128.
            __builtin_amdgcn_s_setprio(1);
            #pragma unroll
            for (int s = 0; s < 4; ++s) {
                const int mt = s >> 1, base = (s & 1) * 4;
                u32x4 pu = {pf[mt][base], pf[mt][base + 1],
                            pf[mt][base + 2], pf[mt][base + 3]};
                bf16x8 pa = __builtin_bit_cast(bf16x8, pu);
                #pragma unroll
                for (int nt = 0; nt < 4; ++nt) {
                    const int d = nt * 32 + l31;
                    const int g = s * 2 + h;
                    bf16x8 vf = *reinterpret_cast<const bf16x8*>(
                        &lds_vt[par][d * 64 + ((g ^ (d & 7)) << 3)]);
                    O[nt] = __builtin_amdgcn_mfma_f32_32x32x16_bf16(
                        pa, vf, O[nt], 0, 0, 0);
                }
            }
            __builtin_amdgcn_s_setprio(0);
        }
        __syncthreads();   // all reads of par done + next-tile DMA drained
        par ^= 1;
    }

    // ---------- epilogue: O / l, f32 out ----------
    {
        float inv = 1.0f / lrow;
        #pragma unroll
        for (int r = 0; r < 16; ++r) {
            const int qr_ = (r & 3) + ((r >> 2) << 3) + hs;
            float li = __shfl(inv, qr_, 64);
            float* orow = out + qbase + (size_t)(i0 + qr_) * HD;
            #pragma unroll
            for (int nt = 0; nt < 4; ++nt)
                orow[nt * 32 + l31] = O[nt][r] * li;
        }
    }
}

// ---------------------------------------------------------------------------
// Fallback (round-6 fused kernel, verbatim): used only if d_ws is too small
// for the 8 MB prep workspace, so the submission never writes out-of-bounds.
// ---------------------------------------------------------------------------
#define KSTR 136
#define VSTR 72
#define VT_ROWS (HD * VSTR + (HD / 4) * 4)
__device__ __forceinline__ int vt_off(int row, int col) {
    return row * VSTR + (row >> 2) * 4 + col;
}

__global__ __launch_bounds__(512, 2)
void fa_mfma_fused(
    const float* __restrict__ q,
    const float* __restrict__ k,
    const float* __restrict__ v,
    float* __restrict__ out)
{
    const int tid  = threadIdx.x;
    const int wave = tid >> 6;
    const int lane = tid & 63;
    const int l4   = lane >> 4;
    const int l15  = lane & 15;

    const int bh   = blockIdx.x >> 4;
    const int qblk = blockIdx.x & 15;
    const int q0   = qblk << 7;
    const int hkv  = (bh & (NH - 1)) >> 2;
    const int b    = bh >> 4;

    const int i0   = q0 + wave * 16;

    __shared__ __align__(16) uint16_t lds_k[2][64 * KSTR];
    __shared__ __align__(16) uint16_t lds_vt[2][VT_ROWS];

    const float scale2 = 0.08838834764831845f * 1.4426950408889634f;

    const size_t qbase  = (size_t)bh * SEQ * HD;
    const size_t kvbase = (size_t)(b * NKV + hkv) * SEQ * HD;

    bf16x8 qf[4];
    {
        const float* qr = q + qbase + (size_t)(i0 + l15) * HD;
        #pragma unroll
        for (int ks = 0; ks < 4; ++ks) {
            const float4* g = reinterpret_cast<const float4*>(qr + ks * 32 + l4 * 8);
            float4 a = g[0], bq = g[1];
            u32x4 t;
            t.x = pk2(a.x * scale2, a.y * scale2);
            t.y = pk2(a.z * scale2, a.w * scale2);
            t.z = pk2(bq.x * scale2, bq.y * scale2);
            t.w = pk2(bq.z * scale2, bq.w * scale2);
            qf[ks] = __builtin_bit_cast(bf16x8, t);
        }
    }

    f32x4 O[8];
    #pragma unroll
    for (int a2 = 0; a2 < 8; ++a2) O[a2] = (f32x4){0.f, 0.f, 0.f, 0.f};
    float mrow = -1e30f;
    float lrow = 0.f;

    const int kt_lo_blk = (q0 >= 512) ? ((q0 - 511) >> 6) : 0;
    const int kt_hi_blk = (q0 + 127) >> 6;
    const int lo_w = (i0 >= 512) ? ((i0 - 511) >> 6) : 0;
    const int hi_w = (i0 + 15) >> 6;

    const int vdg = tid & 31;
    const int vkg = tid >> 5;
    float4 rKa[2], rKb[2], rV[4];

    auto prefetch_k = [&](int kt) {
        const float* kp = k + kvbase + (size_t)kt * 64 * HD;
        #pragma unroll
        for (int it = 0; it < 2; ++it) {
            int flat8 = tid + it * 512, key = flat8 >> 4, ch = flat8 & 15;
            const float4* g = reinterpret_cast<const float4*>(kp + key * HD + ch * 8);
            rKa[it] = g[0]; rKb[it] = g[1];
        }
    };
    auto prefetch_v = [&](int kt) {
        const float* vp = v + kvbase + (size_t)kt * 64 * HD;
        #pragma unroll
        for (int r = 0; r < 4; ++r)
            rV[r] = *reinterpret_cast<const float4*>(vp + (vkg * 4 + r) * HD + vdg * 4);
    };
    auto pack_k = [&](int pb) {
        #pragma unroll
        for (int it = 0; it < 2; ++it) {
            int flat8 = tid + it * 512, key = flat8 >> 4, ch = flat8 & 15;
            uint4 wv;
            wv.x = pk2(rKa[it].x, rKa[it].y);  wv.y = pk2(rKa[it].z, rKa[it].w);
            wv.z = pk2(rKb[it].x, rKb[it].y);  wv.w = pk2(rKb[it].z, rKb[it].w);
            *reinterpret_cast<uint4*>(&lds_k[pb][key * KSTR + ch * 8]) = wv;
        }
    };
    auto pack_v = [&](int pb) {
        const float* rvf = reinterpret_cast<const float*>(rV);
        #pragma unroll
        for (int i = 0; i < 4; ++i) {
            u32x2 wv;
            wv.x = pk2(rvf[0 * 4 + i], rvf[1 * 4 + i]);
            wv.y = pk2(rvf[2 * 4 + i], rvf[3 * 4 + i]);
            *reinterpret_cast<u32x2*>(&lds_vt[pb][vt_off(vdg * 4 + i, vkg * 4)]) = wv;
        }
    };

    prefetch_k(kt_lo_blk);
    prefetch_v(kt_lo_blk);
    pack_k(0);
    pack_v(0);
    __syncthreads();

    int par = 0;
    for (int kt = kt_lo_blk; kt <= kt_hi_blk; ++kt) {
        const bool more = (kt < kt_hi_blk);
        if (more) prefetch_k(kt + 1);

        if (kt >= lo_w && kt <= hi_w) {
            f32x4 sf[4];
            #pragma unroll
            for (int mt = 0; mt < 4; ++mt) sf[mt] = (f32x4){0.f, 0.f, 0.f, 0.f};
            __builtin_amdgcn_s_setprio(1);
            #pragma unroll
            for (int mt = 0; mt < 4; ++mt) {
                #pragma unroll
                for (int ks = 0; ks < 4; ++ks) {
                    bf16x8 af = *reinterpret_cast<const bf16x8*>(
                        &lds_k[par][(mt * 16 + l15) * KSTR + ks * 32 + l4 * 8]);
                    sf[mt] = __builtin_amdgcn_mfma_f32_16x16x32_bf16(
                        af, qf[ks], sf[mt], 0, 0, 0);
                }
            }
            __builtin_amdgcn_s_setprio(0);
            if (more) { pack_k(par ^ 1); prefetch_v(kt + 1); }
            const bool needmask = (kt == hi_w) || (kt == lo_w && i0 > 511);
            if (needmask) {
                const int iq = i0 + l15;
                #pragma unroll
                for (int mt = 0; mt < 4; ++mt) {
                    int jb = kt * 64 + mt * 16 + l4 * 4;
                    #pragma unroll
                    for (int r = 0; r < 4; ++r) {
                        int j = jb + r;
                        if (!((j <= iq) && (iq - j < WIN))) sf[mt][r] = -1e30f;
                    }
                }
            }
            float a0 = fmaxf(fmaxf(sf[0][0], sf[0][1]), fmaxf(sf[0][2], sf[0][3]));
            float a1 = fmaxf(fmaxf(sf[1][0], sf[1][1]), fmaxf(sf[1][2], sf[1][3]));
            float a2 = fmaxf(fmaxf(sf[2][0], sf[2][1]), fmaxf(sf[2][2], sf[2][3]));
            float a3 = fmaxf(fmaxf(sf[3][0], sf[3][1]), fmaxf(sf[3][2], sf[3][3]));
            float tm = fmaxf(fmaxf(a0, a1), fmaxf(a2, a3));
            tm = fmaxf(tm, __shfl_xor(tm, 16, 64));
            tm = fmaxf(tm, __shfl_xor(tm, 32, 64));
            const bool defer = __all(tm <= mrow + 8.0f);
            if (!defer) {
                float mn = fmaxf(mrow, tm);
                float alpha = EXP2(mrow - mn);
                mrow = mn;
                lrow *= alpha;
                #pragma unroll
                for (int r = 0; r < 4; ++r) {
                    float ar = __shfl(alpha, l4 * 4 + r, 64);
                    #pragma unroll
                    for (int nt = 0; nt < 8; ++nt) O[nt][r] *= ar;
                }
            }
            bf16x4 pfrag[4];
            {
                float me = fmaxf(mrow, -1e20f);
                float s[4];
                #pragma unroll
                for (int mt = 0; mt < 4; ++mt) {
                    float p0 = EXP2(sf[mt][0] - me);
                    float p1 = EXP2(sf[mt][1] - me);
                    float p2 = EXP2(sf[mt][2] - me);
                    float p3 = EXP2(sf[mt][3] - me);
                    u32x2 t;
                    t.x = pk2(p0, p1);
                    t.y = pk2(p2, p3);
                    pfrag[mt] = __builtin_bit_cast(bf16x4, t);
                    s[mt] = (p0 + p1) + (p2 + p3);
                }
                float ts = (s[0] + s[1]) + (s[2] + s[3]);
                ts += __shfl_xor(ts, 16, 64);
                ts += __shfl_xor(ts, 32, 64);
                lrow += ts;
            }
            if (more) pack_v(par ^ 1);
            __builtin_amdgcn_s_setprio(1);
            #pragma unroll
            for (int s = 0; s < 2; ++s) {
                bf16x8 pa = __builtin_shufflevector(pfrag[2 * s], pfrag[2 * s + 1],
                                                    0, 1, 2, 3, 4, 5, 6, 7);
                #pragma unroll
                for (int nt = 0; nt < 8; ++nt) {
                    const int vr = nt * 16 + l15;
                    bf16x4 v0 = *reinterpret_cast<const bf16x4*>(
                        &lds_vt[par][vt_off(vr, s * 32 + l4 * 4)]);
                    bf16x4 v1 = *reinterpret_cast<const bf16x4*>(
                        &lds_vt[par][vt_off(vr, s * 32 + 16 + l4 * 4)]);
                    bf16x8 vf = __builtin_shufflevector(v0, v1, 0, 1, 2, 3, 4, 5, 6, 7);
                    O[nt] = __builtin_amdgcn_mfma_f32_16x16x32_bf16(pa, vf, O[nt], 0, 0, 0);
                }
            }
            __builtin_amdgcn_s_setprio(0);
        } else {
            if (more) { prefetch_v(kt + 1); pack_k(par ^ 1); pack_v(par ^ 1); }
        }
        __syncthreads();
        par ^= 1;
    }

    {
        float inv = 1.0f / lrow;
        #pragma unroll
        for (int r = 0; r < 4; ++r) {
            float li = __shfl(inv, l4 * 4 + r, 64);
            int row = i0 + l4 * 4 + r;
            float* orow = out + qbase + (size_t)row * HD;
            #pragma unroll
            for (int nt = 0; nt < 8; ++nt)
                orow[nt * 16 + l15] = O[nt][r] * li;
        }
    }
}

extern "C" void kernel_launch(void* const* d_in, const int* in_sizes, int n_in,
                              void* d_out, int out_size, void* d_ws, size_t ws_size,
                              hipStream_t stream) {
    const float* q = (const float*)d_in[0];
    const float* k = (const float*)d_in[1];
    const float* v = (const float*)d_in[2];
    float* out     = (float*)d_out;

    const size_t kv_elems = (size_t)BATCH * NKV * SEQ * HD;    // 2,097,152
    const size_t ws_needed = kv_elems * 2u * sizeof(uint16_t); // 8 MB

    if (d_ws != nullptr && ws_size >= ws_needed) {
        uint16_t* kb  = (uint16_t*)d_ws;           // 4 MB
        uint16_t* vtw = kb + kv_elems;             // 4 MB
        hipLaunchKernelGGL(prep_kv, dim3(BATCH * NKV * (SEQ / 64)), dim3(256), 0,
                           stream, k, v, kb, vtw);
        hipLaunchKernelGGL(fa_mfma, dim3(BATCH * NH * (SEQ / 128)), dim3(256), 0,
                           stream, q, kb, vtw, out);
    } else {
        hipLaunchKernelGGL(fa_mfma_fused, dim3(BATCH * NH * (SEQ / 128)), dim3(512),
                           0, stream, q, k, v, out);
    }
}